// Round 3
// baseline (8276.244 us; speedup 1.0000x reference)
//
#include <hip/hip_runtime.h>
#include <hip/hip_bf16.h>

// Problem: 2-layer LSTM. ys from lax.scan is (T, B, H); ys[:, -1, :] selects BATCH 63,
// all T=512 timesteps. Output = logits[t, o] = h1[t, batch63] @ Wd + bd, (512, 512) fp32.
// Only batch 63's recurrence matters -> latency-bound serial chain of 2 GEMVs x 512 steps.

#define TSTEPS 512
#define NBLK   256

typedef short bf16x8 __attribute__((ext_vector_type(8)));
typedef float f32x4  __attribute__((ext_vector_type(4)));

// ---- workspace layout (bytes) ----
#define WS_PW    0u          // packed weights: 256cu * 4w * 28slot * 64lane * 16B = 29360128
#define WS_H0    29360128u   // h0 ping-pong [2][1024] bf16 = 4096
#define WS_H1    29364224u   // h1 ping-pong [2][1024] bf16 = 4096
#define WS_CNT   29368320u   // barrier counter (4 B, padded to 256)
#define WS_H1ALL 29368576u   // h1 trajectory [512][1024] bf16 = 1048576
#define WS_XB    30417152u   // batch-63 X in bf16: 512*512*2 = 524288
#define WS_END   30941440u

__device__ __forceinline__ unsigned short f2b(float x) {
  unsigned int u = __builtin_bit_cast(unsigned int, x);
  unsigned int r = (u + 0x7FFFu + ((u >> 16) & 1u)) >> 16;   // RNE
  return (unsigned short)r;
}
__device__ __forceinline__ float b2f(unsigned short u) {
  return __builtin_bit_cast(float, (unsigned int)u << 16);
}

// ---- prep: pack W0/W1 (fp32) into per-(cu,wave,slot,lane) bf16 MFMA B-fragments ----
// Slot map (per cu, wave w):
//   i in [0,4):   L0 x-part,  W0 rows k = w*128 + i*32 + q*8 + e
//   i in [4,12):  L0 h0-part, W0 rows k = 512 + w*256 + (i-4)*32 + q*8 + e
//   i in [12,20): L1 h0-part, W1 rows k = w*256 + (i-12)*32 + q*8 + e
//   i in [20,28): L1 h1-part, W1 rows k = 1024 + w*256 + (i-20)*32 + q*8 + e
// Column n = g*1024 + cu*4 + j with vc = lane&15, j = vc>>2, g = vc&3 (gate order i,j,f,o).
__global__ __launch_bounds__(256) void kpack(const float* __restrict__ W0,
                                             const float* __restrict__ W1,
                                             uint4* __restrict__ pw) {
  const int t    = blockIdx.x * 256 + threadIdx.x;   // 0..1835007
  const int lane = t & 63;
  const int rest = t >> 6;
  const int i    = rest % 28;
  const int cw   = rest / 28;          // cu*4 + w
  const int w    = cw & 3;
  const int cu   = cw >> 2;
  const int q  = lane >> 4, vc = lane & 15;
  const int n  = (vc & 3) * 1024 + (cu << 2) + (vc >> 2);
  const float* src; int k0;
  if (i < 4)       { src = W0; k0 = w * 128 + i * 32; }
  else if (i < 12) { src = W0; k0 = 512 + w * 256 + (i - 4) * 32; }
  else if (i < 20) { src = W1; k0 = w * 256 + (i - 12) * 32; }
  else             { src = W1; k0 = 1024 + w * 256 + (i - 20) * 32; }
  k0 += q * 8;
  unsigned int wd[4];
#pragma unroll
  for (int e2 = 0; e2 < 4; ++e2) {
    unsigned int lo = f2b(src[(size_t)(k0 + 2 * e2    ) * 4096 + n]);
    unsigned int hi = f2b(src[(size_t)(k0 + 2 * e2 + 1) * 4096 + n]);
    wd[e2] = lo | (hi << 16);
  }
  uint4 v; v.x = wd[0]; v.y = wd[1]; v.z = wd[2]; v.w = wd[3];
  pw[t] = v;
}

// ---- prep: batch-63 X slice fp32 -> bf16 ----
__global__ __launch_bounds__(256) void kconvX63(const float* __restrict__ X63,
                                                unsigned short* __restrict__ Xb) {
  const int i = blockIdx.x * 256 + threadIdx.x;      // 65536 x 4 elems
  const float4 v = reinterpret_cast<const float4*>(X63)[i];
  ushort4 o;
  o.x = f2b(v.x); o.y = f2b(v.y); o.z = f2b(v.z); o.w = f2b(v.w);
  reinterpret_cast<ushort4*>(Xb)[i] = o;
}

// ---- prep: init h buffers from state row 63, zero barrier counter ----
__global__ __launch_bounds__(1024) void kinith(const float* __restrict__ state63,
    unsigned short* __restrict__ h0, unsigned short* __restrict__ h1,
    unsigned int* __restrict__ cnt) {
  const int i = threadIdx.x;                         // 0..1023
  unsigned short v0 = f2b(state63[1024 + i]);        // h0 init
  unsigned short v1 = f2b(state63[3072 + i]);        // h1 init
  h0[i] = v0; h0[1024 + i] = v0;
  h1[i] = v1; h1[1024 + i] = v1;
  if (i == 0) *cnt = 0u;
}

// ---- persistent batch-63 2-layer LSTM ----
// 256 blocks (1/CU via 88KB dyn LDS) x 256 threads (4 waves).
// Weights live in VGPRs (28 uint4/thread). Phase p: layer0 step p (p<512) and
// layer1 step p-1 (p>=1); one counter barrier per phase (513 total).
// GEMV-by-MFMA: all 16 A-rows carry the same activation slice -> every D row equals z.
__global__ __launch_bounds__(256, 1) void klstm(
    const float* __restrict__ X63,               // fp32 fallback path
    const unsigned short* __restrict__ Xb63,     // bf16 [512][512]
    const int useXb,
    const uint4* __restrict__ pw,
    unsigned short* __restrict__ h0buf,          // [2][1024]
    unsigned short* __restrict__ h1buf,          // [2][1024]
    unsigned short* __restrict__ h1all,          // [512][1024] bf16
    const float* __restrict__ state63,
    const float* __restrict__ b0, const float* __restrict__ b1,
    unsigned int* __restrict__ cnt)
{
  extern __shared__ float lds[];                 // use first 256 floats (2 parity x 128)
  const int cu   = blockIdx.x;
  const int tid  = threadIdx.x;
  const int lane = tid & 63;
  const int wid  = tid >> 6;
  const int q = lane >> 4;

  // resident weights: 28 fragments x 16B
  uint4 wreg[28];
#pragma unroll
  for (int i = 0; i < 28; ++i)
    wreg[i] = pw[(((cu << 2) | wid) * 28 + i) * 64 + lane];

  // cell-duty lanes: wave 0, lanes 0..31.  li<16: layer0 cols, li>=16: layer1.
  const int li    = lane & 31;
  const int layer = li >> 4;
  const int cvc   = li & 15;
  const int cj = cvc >> 2, cg = cvc & 3;
  const int hc = (cu << 2) | cj;
  float cstate = 0.f, bias = 0.f;
  if (wid == 0 && lane < 32) {
    cstate = state63[layer * 2048 + hc];               // c0 @0, c1 @2048
    bias   = (layer == 0 ? b0 : b1)[cg * 1024 + hc];
  }

  // depth-1 x prefetch (bf16 path): 4 x uint4 per lane
  const unsigned short* xb = Xb63 + wid * 128 + q * 8;
  uint4 xcur[4], xnxt[4];
  if (useXb) {
#pragma unroll
    for (int i = 0; i < 4; ++i)
      xcur[i] = *reinterpret_cast<const uint4*>(xb + i * 32);
  }

  for (int p = 0; p <= TSTEPS; ++p) {
    if (p > 0) {                                       // wait: all blocks finished p-1
      if (tid == 0) {
        const unsigned int target = (unsigned int)p * NBLK;
        int guard = 0;
        while (__hip_atomic_load(cnt, __ATOMIC_RELAXED, __HIP_MEMORY_SCOPE_AGENT) < target
               && ++guard < (1 << 16))
          __builtin_amdgcn_s_sleep(1);
      }
      __syncthreads();
      __builtin_amdgcn_fence(__ATOMIC_ACQUIRE, "agent");
    }

    const unsigned short* h0rd = h0buf + (((p & 1) ^ 1) << 10);  // h0[p-1]
    unsigned short*       h0wr = h0buf + ((p & 1) << 10);        // h0[p]
    const unsigned short* h1rd = h1buf + ((p & 1) << 10);        // h1[p-2]
    unsigned short*       h1wr = h1buf + (((p & 1) ^ 1) << 10);  // h1[p-1]
    const bool do0 = (p < TSTEPS);
    const bool do1 = (p >= 1);

    // issue next-phase x loads early (overlap with h reads + MFMA)
    if (useXb && (p + 1 < TSTEPS)) {
#pragma unroll
      for (int i = 0; i < 4; ++i)
        xnxt[i] = *reinterpret_cast<const uint4*>(xb + (p + 1) * 512 + i * 32);
    }

    f32x4 acc0 = {0.f, 0.f, 0.f, 0.f};
    f32x4 acc1 = {0.f, 0.f, 0.f, 0.f};

    // A fragments (same 16B in all 16 row-lanes of each quad -> broadcast GEMV)
    bf16x8 ax[4], ah0[8], ah1[8];
    if (do0) {
      if (useXb) {
#pragma unroll
        for (int i = 0; i < 4; ++i) ax[i] = __builtin_bit_cast(bf16x8, xcur[i]);
      } else {
        const float* xs = X63 + p * 512 + wid * 128 + q * 8;
#pragma unroll
        for (int i = 0; i < 4; ++i) {
          float4 f0 = *reinterpret_cast<const float4*>(xs + i * 32);
          float4 f1 = *reinterpret_cast<const float4*>(xs + i * 32 + 4);
          bf16x8 a;
          a[0] = (short)f2b(f0.x); a[1] = (short)f2b(f0.y);
          a[2] = (short)f2b(f0.z); a[3] = (short)f2b(f0.w);
          a[4] = (short)f2b(f1.x); a[5] = (short)f2b(f1.y);
          a[6] = (short)f2b(f1.z); a[7] = (short)f2b(f1.w);
          ax[i] = a;
        }
      }
    }
    {   // h0[p-1] slice: shared by L0 (slots 4..11) and L1 (slots 12..19)
      const unsigned short* hs = h0rd + wid * 256 + q * 8;
#pragma unroll
      for (int i = 0; i < 8; ++i)
        ah0[i] = *reinterpret_cast<const bf16x8*>(hs + i * 32);
    }
    if (do1) {
      const unsigned short* hs = h1rd + wid * 256 + q * 8;
#pragma unroll
      for (int i = 0; i < 8; ++i)
        ah1[i] = *reinterpret_cast<const bf16x8*>(hs + i * 32);
    }

    if (do0) {
#pragma unroll
      for (int i = 0; i < 4; ++i)
        acc0 = __builtin_amdgcn_mfma_f32_16x16x32_bf16(
            ax[i], __builtin_bit_cast(bf16x8, wreg[i]), acc0, 0, 0, 0);
#pragma unroll
      for (int i = 0; i < 8; ++i)
        acc0 = __builtin_amdgcn_mfma_f32_16x16x32_bf16(
            ah0[i], __builtin_bit_cast(bf16x8, wreg[4 + i]), acc0, 0, 0, 0);
    }
    if (do1) {
#pragma unroll
      for (int i = 0; i < 8; ++i) {
        acc1 = __builtin_amdgcn_mfma_f32_16x16x32_bf16(
            ah0[i], __builtin_bit_cast(bf16x8, wreg[12 + i]), acc1, 0, 0, 0);
        acc1 = __builtin_amdgcn_mfma_f32_16x16x32_bf16(
            ah1[i], __builtin_bit_cast(bf16x8, wreg[20 + i]), acc1, 0, 0, 0);
      }
    }

    // cross-wave partial exchange (all D rows equal -> take acc[0] from lanes 0..15)
    float* part = lds + ((p & 1) << 7);
    if (lane < 16) {
      part[wid * 16 + lane]      = acc0[0];
      part[64 + wid * 16 + lane] = acc1[0];
    }
    __syncthreads();

    if (wid == 0 && lane < 32) {
      float z = bias;
#pragma unroll
      for (int w = 0; w < 4; ++w) z += part[layer * 64 + w * 16 + cvc];
      // gather 4 gates of this h-col (adjacent lanes, cg = lane&3)
      float a1 = __shfl_xor(z, 1);
      float a2 = __shfl_xor(z, 2);
      float a3 = __shfl_xor(z, 3);
      float zi = (cg == 0) ? z : (cg == 1) ? a1 : (cg == 2) ? a2 : a3;
      float zj = (cg == 1) ? z : (cg == 0) ? a1 : (cg == 3) ? a2 : a3;
      float zf = (cg == 2) ? z : (cg == 3) ? a1 : (cg == 0) ? a2 : a3;
      float zo = (cg == 3) ? z : (cg == 2) ? a1 : (cg == 1) ? a2 : a3;
      const bool act = layer ? do1 : do0;
      float ig = 1.f / (1.f + __expf(-zi));
      float jt = 1.f - 2.f / (1.f + __expf(2.f * zj));
      float fg = 1.f / (1.f + __expf(-(zf + 1.0f)));      // FORGET_BIAS = 1
      float og = 1.f / (1.f + __expf(-zo));
      float c2 = fg * cstate + ig * jt;
      float h2 = og * (1.f - 2.f / (1.f + __expf(2.f * c2)));
      if (act) {
        cstate = c2;
        if (cg == 0) {
          if (layer == 0) {
            h0wr[hc] = f2b(h2);
          } else {
            unsigned short hb = f2b(h2);
            h1wr[hc] = hb;
            h1all[(p - 1) * 1024 + hc] = hb;
          }
        }
      }
    }

    if (tid == 0)   // release: wave-0's h stores drained + L2 writeback, then arrive
      __hip_atomic_fetch_add(cnt, 1u, __ATOMIC_RELEASE, __HIP_MEMORY_SCOPE_AGENT);

    if (useXb && (p + 1 < TSTEPS)) {
#pragma unroll
      for (int i = 0; i < 4; ++i) xcur[i] = xnxt[i];
    }
  }
}

// ---- logits[t, o] = h1all[t, :] @ Wd + bd ;  (512x1024)@(1024x512) ----
__global__ __launch_bounds__(256) void klogits(const unsigned short* __restrict__ h1all,
                                               const float* __restrict__ Wd,
                                               const float* __restrict__ bd,
                                               float* __restrict__ out) {
  __shared__ float hs[16][128];
  const int t  = threadIdx.x;
  const int o  = blockIdx.x * 64 + (t & 63);
  const int rq = t >> 6;                         // 0..3
  const int r0 = blockIdx.y * 16;
  float acc[4] = {0.f, 0.f, 0.f, 0.f};
  for (int kc = 0; kc < 8; ++kc) {
    __syncthreads();
#pragma unroll
    for (int i = 0; i < 8; ++i) {
      int e = i * 256 + t;                       // 2048 elems, coalesced
      hs[e >> 7][e & 127] = b2f(h1all[(r0 + (e >> 7)) * 1024 + kc * 128 + (e & 127)]);
    }
    __syncthreads();
    for (int k = 0; k < 128; ++k) {
      float w = Wd[(size_t)(kc * 128 + k) * 512 + o];
#pragma unroll
      for (int r = 0; r < 4; ++r) acc[r] += hs[rq * 4 + r][k] * w;
    }
  }
  const float bv = bd[o];
#pragma unroll
  for (int r = 0; r < 4; ++r)
    out[(size_t)(r0 + rq * 4 + r) * 512 + o] = acc[r] + bv;
}

extern "C" void kernel_launch(void* const* d_in, const int* in_sizes, int n_in,
                              void* d_out, int out_size, void* d_ws, size_t ws_size,
                              hipStream_t stream) {
  (void)in_sizes; (void)n_in; (void)out_size;
  const float* X  = (const float*)d_in[0];
  const float* st = (const float*)d_in[1];
  const float* W0 = (const float*)d_in[2];
  const float* b0 = (const float*)d_in[3];
  const float* W1 = (const float*)d_in[4];
  const float* b1 = (const float*)d_in[5];
  const float* Wd = (const float*)d_in[6];
  const float* bd = (const float*)d_in[7];
  float* out = (float*)d_out;
  unsigned char* ws = (unsigned char*)d_ws;

  uint4*          pw    = (uint4*)(ws + WS_PW);
  unsigned short* h0buf = (unsigned short*)(ws + WS_H0);
  unsigned short* h1buf = (unsigned short*)(ws + WS_H1);
  unsigned int*   cnt   = (unsigned int*)(ws + WS_CNT);
  unsigned short* h1all = (unsigned short*)(ws + WS_H1ALL);
  unsigned short* Xb63  = (unsigned short*)(ws + WS_XB);

  const float* X63     = X  + (size_t)63 * TSTEPS * 512;
  const float* state63 = st + (size_t)63 * 4096;

  const int useXb = (ws_size >= (size_t)WS_END) ? 1 : 0;   // ws_size fixed -> uniform per call

  kpack<<<7168, 256, 0, stream>>>(W0, W1, pw);
  if (useXb) kconvX63<<<256, 256, 0, stream>>>(X63, Xb63);
  kinith<<<1, 1024, 0, stream>>>(state63, h0buf, h1buf, cnt);

  hipFuncSetAttribute((const void*)klstm, hipFuncAttributeMaxDynamicSharedMemorySize, 90112);
  klstm<<<NBLK, 256, 90112, stream>>>(X63, Xb63, useXb, pw, h0buf, h1buf, h1all,
                                      state63, b0, b1, cnt);

  klogits<<<dim3(8, 32), 256, 0, stream>>>(h1all, Wd, bd, out);
}

// Round 4
// 3175.362 us; speedup vs baseline: 2.6064x; 2.6064x over previous
//
#include <hip/hip_runtime.h>
#include <hip/hip_bf16.h>

// Problem: 2-layer LSTM. ys from lax.scan is (T, B, H); ys[:, -1, :] selects BATCH 63,
// all T=512 steps. Output logits[t, o] = h1[t] @ Wd + bd, (512, 512) fp32.
// Latency-bound serial chain: 513 pipelined phases (L0 step p || L1 step p-1).
// Cross-block exchange via TAGGED 16B lines with sc0/sc1 (LLC-coherent, no fences,
// no atomics, no bulk wbl2/inv): {4 bf16 h-cols, pad, phase tag} per dwordx4.

#define TSTEPS 512

typedef short bf16x8 __attribute__((ext_vector_type(8)));
typedef float f32x4  __attribute__((ext_vector_type(4)));
typedef unsigned int u32x4 __attribute__((ext_vector_type(4)));

// ---- workspace layout (bytes) ----
#define WS_PW    0u          // packed weights: 256cu*4w*28slot*64lane*16B = 29360128
#define WS_XCH   29360128u   // exchange: 1024 lines x 16B (A:slot0,slot1 | B:slot0,slot1)
#define WS_H1ALL 29376512u   // h1 trajectory [512][1024] bf16 = 1048576
#define WS_XB    30425088u   // batch-63 X in bf16: 512*512*2 = 524288
#define WS_END   30949376u

__device__ __forceinline__ unsigned short f2b(float x) {
  unsigned int u = __builtin_bit_cast(unsigned int, x);
  unsigned int r = (u + 0x7FFFu + ((u >> 16) & 1u)) >> 16;   // RNE
  return (unsigned short)r;
}
__device__ __forceinline__ float b2f(unsigned short u) {
  return __builtin_bit_cast(float, (unsigned int)u << 16);
}

// LLC-coherent (cache-bypassing) 16B load/store: sc0 sc1 on gfx950.
__device__ __forceinline__ u32x4 load_sc(const u32x4* p) {
  u32x4 r;
  asm volatile("global_load_dwordx4 %0, %1, off sc0 sc1" : "=v"(r) : "v"(p));
  return r;
}
__device__ __forceinline__ void store_sc(u32x4* p, u32x4 v) {
  asm volatile("global_store_dwordx4 %0, %1, off sc0 sc1" :: "v"(p), "v"(v) : "memory");
}

// ---- prep: pack W0/W1 (fp32) into per-(cu,wave,slot,lane) bf16 MFMA B-fragments ----
// k-permutation pi chosen so each consumer lane's h-columns are CONTIGUOUS:
//   x  slots i in [0,4):   W0 row k = w*128 + i*32 + q*8 + e            (x private, dense)
//   h0 slots i in [4,12):  W0 row k = 512 + w*256 + q*64 + (i-4)*8 + e
//   h0 slots i in [12,20): W1 row k = w*256 + q*64 + (i-12)*8 + e
//   h1 slots i in [20,28): W1 row k = 1024 + w*256 + q*64 + (i-20)*8 + e
// Column n = g*1024 + cu*4 + j with vc=lane&15, j=vc>>2, g=vc&3 (gate order i,j,f,o).
__global__ __launch_bounds__(256) void kpack(const float* __restrict__ W0,
                                             const float* __restrict__ W1,
                                             uint4* __restrict__ pw) {
  const int t    = blockIdx.x * 256 + threadIdx.x;   // 0..1835007
  const int lane = t & 63;
  const int rest = t >> 6;
  const int i    = rest % 28;
  const int cw   = rest / 28;          // cu*4 + w
  const int w    = cw & 3;
  const int cu   = cw >> 2;
  const int q  = lane >> 4, vc = lane & 15;
  const int n  = (vc & 3) * 1024 + (cu << 2) + (vc >> 2);
  const float* src; int k0;
  if (i < 4)       { src = W0; k0 = w * 128 + i * 32 + q * 8; }
  else if (i < 12) { src = W0; k0 = 512 + w * 256 + q * 64 + (i - 4) * 8; }
  else if (i < 20) { src = W1; k0 = w * 256 + q * 64 + (i - 12) * 8; }
  else             { src = W1; k0 = 1024 + w * 256 + q * 64 + (i - 20) * 8; }
  unsigned int wd[4];
#pragma unroll
  for (int e2 = 0; e2 < 4; ++e2) {
    unsigned int lo = f2b(src[(size_t)(k0 + 2 * e2    ) * 4096 + n]);
    unsigned int hi = f2b(src[(size_t)(k0 + 2 * e2 + 1) * 4096 + n]);
    wd[e2] = lo | (hi << 16);
  }
  uint4 v; v.x = wd[0]; v.y = wd[1]; v.z = wd[2]; v.w = wd[3];
  pw[t] = v;
}

// ---- prep: batch-63 X slice fp32 -> bf16 ----
__global__ __launch_bounds__(256) void kconvX63(const float* __restrict__ X63,
                                                unsigned short* __restrict__ Xb) {
  const int i = blockIdx.x * 256 + threadIdx.x;
  const float4 v = reinterpret_cast<const float4*>(X63)[i];
  ushort4 o;
  o.x = f2b(v.x); o.y = f2b(v.y); o.z = f2b(v.z); o.w = f2b(v.w);
  reinterpret_cast<ushort4*>(Xb)[i] = o;
}

// ---- prep: init exchange lines. Lines [0,256)=A slot0, [256,512)=A slot1,
// [512,768)=B slot0, [768,1024)=B slot1. Tags MUST be zeroed (ws poisoned 0xAA).
// A-slot1 carries initial h0 (consumed phase 0); B-slot1 tag 0 passes trivially.
__global__ __launch_bounds__(1024) void kinith(const float* __restrict__ state63,
                                               u32x4* __restrict__ xch) {
  const int i  = threadIdx.x;            // 0..1023
  const int rg = i >> 8, cu = i & 255;
  u32x4 v = {0u, 0u, 0u, 0u};
  if (rg == 1) {                         // initial h0
    v.x = (unsigned)f2b(state63[1024 + 4*cu])     | ((unsigned)f2b(state63[1024 + 4*cu + 1]) << 16);
    v.y = (unsigned)f2b(state63[1024 + 4*cu + 2]) | ((unsigned)f2b(state63[1024 + 4*cu + 3]) << 16);
  } else if (rg == 3) {                  // initial h1 (data unused, tag matters)
    v.x = (unsigned)f2b(state63[3072 + 4*cu])     | ((unsigned)f2b(state63[3072 + 4*cu + 1]) << 16);
    v.y = (unsigned)f2b(state63[3072 + 4*cu + 2]) | ((unsigned)f2b(state63[3072 + 4*cu + 3]) << 16);
  }
  xch[i] = v;
}

// ---- persistent batch-63 2-layer LSTM ----
// 256 blocks (1/CU via 88KB dyn LDS) x 256 threads (4 waves). Weights in VGPRs.
// Phase p: L0 step p (p<512) and L1 step p-1 (p>=1). No fences/atomics: consumers
// poll their 16+16 tagged lines until tag >= p; producers store data+tag atomically.
__global__ __launch_bounds__(256, 1) void klstm(
    const float* __restrict__ X63,               // fp32 fallback
    const unsigned short* __restrict__ Xb63,     // bf16 [512][512]
    const int useXb,
    const uint4* __restrict__ pw,
    u32x4* __restrict__ xch,
    unsigned short* __restrict__ h1all,          // [512][1024] bf16
    const float* __restrict__ state63,
    const float* __restrict__ b0, const float* __restrict__ b1)
{
  extern __shared__ float lds[];                 // partials: 2 parity x 128 floats
  const int cu   = blockIdx.x;
  const int tid  = threadIdx.x;
  const int lane = tid & 63;
  const int wid  = tid >> 6;
  const int q = lane >> 4, vc = lane & 15;
  const int cg = vc & 3;
  const int hc = (cu << 2) | (vc >> 2);

  uint4 wreg[28];
#pragma unroll
  for (int i = 0; i < 28; ++i)
    wreg[i] = pw[(((cu << 2) | wid) * 28 + i) * 64 + lane];

  // wave0 mirrors layer0 cell across all 64 lanes; wave1 mirrors layer1.
  float cstate = 0.f, bias = 0.f, h1init = 0.f;
  if (wid == 0) { cstate = state63[hc];        bias = b0[cg * 1024 + hc]; }
  if (wid == 1) { cstate = state63[2048 + hc]; bias = b1[cg * 1024 + hc];
                  h1init = state63[3072 + hc]; }

  const int lbase = (wid << 6) | (q << 4);     // first exchange line of this lane's window
  const unsigned short* xb = Xb63 + (wid << 7) + (q << 3);

  uint4 xcur[4], xnxt[4];
  if (useXb) {
#pragma unroll
    for (int i = 0; i < 4; ++i)
      xcur[i] = *reinterpret_cast<const uint4*>(xb + i * 32);
  }

  for (int p = 0; p <= TSTEPS; ++p) {
    const bool do0 = (p < TSTEPS);
    const bool do1 = (p >= 1);
    f32x4 acc0 = {0.f, 0.f, 0.f, 0.f};
    f32x4 acc1 = {0.f, 0.f, 0.f, 0.f};

    // x-part MFMAs first (independent of the exchange)
    if (do0) {
      bf16x8 ax[4];
      if (useXb) {
#pragma unroll
        for (int i = 0; i < 4; ++i) ax[i] = __builtin_bit_cast(bf16x8, xcur[i]);
      } else {
        const float* xs = X63 + p * 512 + (wid << 7) + (q << 3);
#pragma unroll
        for (int i = 0; i < 4; ++i) {
          float4 f0 = *reinterpret_cast<const float4*>(xs + i * 32);
          float4 f1 = *reinterpret_cast<const float4*>(xs + i * 32 + 4);
          bf16x8 a;
          a[0] = (short)f2b(f0.x); a[1] = (short)f2b(f0.y);
          a[2] = (short)f2b(f0.z); a[3] = (short)f2b(f0.w);
          a[4] = (short)f2b(f1.x); a[5] = (short)f2b(f1.y);
          a[6] = (short)f2b(f1.z); a[7] = (short)f2b(f1.w);
          ax[i] = a;
        }
      }
#pragma unroll
      for (int i = 0; i < 4; ++i)
        acc0 = __builtin_amdgcn_mfma_f32_16x16x32_bf16(
            ax[i], __builtin_bit_cast(bf16x8, wreg[i]), acc0, 0, 0, 0);
    }

    // ---- tagged poll: my 16 h0-lines + 16 h1-lines, until all tags >= p ----
    const int slotR = (p + 1) & 1;
    const u32x4* baA = xch + slotR * 256 + lbase;
    const u32x4* baB = xch + 512 + slotR * 256 + lbase;
    u32x4 la[16], lb[16];
    const unsigned tgt = (unsigned)p;
    int guard = 0;
    while (true) {
#pragma unroll
      for (int j = 0; j < 16; ++j) la[j] = load_sc(baA + j);
#pragma unroll
      for (int j = 0; j < 16; ++j) lb[j] = load_sc(baB + j);
      asm volatile("s_waitcnt vmcnt(0)" ::: "memory");
      __builtin_amdgcn_sched_barrier(0);
      bool ok = true;
#pragma unroll
      for (int j = 0; j < 16; ++j)
        ok = ok && (la[j].w >= tgt) && (lb[j].w >= tgt);
      if (__all(ok) || ++guard > (1 << 14)) break;
    }

    // next-phase x prefetch (after the poll's vmcnt(0) so it doesn't stall it)
    if (useXb && (p + 1 < TSTEPS)) {
#pragma unroll
      for (int i = 0; i < 4; ++i)
        xnxt[i] = *reinterpret_cast<const uint4*>(xb + (size_t)(p + 1) * 512 + i * 32);
    }

    // assemble contiguous-column fragments (lane window: 64 h-cols = 16 lines)
    bf16x8 ah0[8], ah1[8];
#pragma unroll
    for (int i = 0; i < 8; ++i) {
      u32x4 va = {la[2*i].x, la[2*i].y, la[2*i+1].x, la[2*i+1].y};
      u32x4 vb = {lb[2*i].x, lb[2*i].y, lb[2*i+1].x, lb[2*i+1].y};
      ah0[i] = __builtin_bit_cast(bf16x8, va);
      ah1[i] = __builtin_bit_cast(bf16x8, vb);
    }

    if (do0) {
#pragma unroll
      for (int i = 0; i < 8; ++i)
        acc0 = __builtin_amdgcn_mfma_f32_16x16x32_bf16(
            ah0[i], __builtin_bit_cast(bf16x8, wreg[4 + i]), acc0, 0, 0, 0);
    }
    if (do1) {
#pragma unroll
      for (int i = 0; i < 8; ++i) {
        acc1 = __builtin_amdgcn_mfma_f32_16x16x32_bf16(
            ah0[i], __builtin_bit_cast(bf16x8, wreg[12 + i]), acc1, 0, 0, 0);
        acc1 = __builtin_amdgcn_mfma_f32_16x16x32_bf16(
            ah1[i], __builtin_bit_cast(bf16x8, wreg[20 + i]), acc1, 0, 0, 0);
      }
    }

    // cross-wave partials (parity-doubled LDS; single sync per phase)
    float* part = lds + ((p & 1) << 7);
    if (lane < 16) {
      part[(wid << 4) | lane]      = acc0[0];
      part[64 + ((wid << 4) | lane)] = acc1[0];
    }
    __syncthreads();

    // cell update + publish: wave0 = layer0, wave1 = layer1 (all 64 lanes mirror)
    if (wid < 2) {
      float z = bias;
#pragma unroll
      for (int w2 = 0; w2 < 4; ++w2) z += part[(wid << 6) + w2 * 16 + vc];
      float a1 = __shfl_xor(z, 1);
      float a2 = __shfl_xor(z, 2);
      float a3 = __shfl_xor(z, 3);
      float zi = (cg == 0) ? z : (cg == 1) ? a1 : (cg == 2) ? a2 : a3;
      float zj = (cg == 1) ? z : (cg == 0) ? a1 : (cg == 3) ? a2 : a3;
      float zf = (cg == 2) ? z : (cg == 3) ? a1 : (cg == 0) ? a2 : a3;
      float zo = (cg == 3) ? z : (cg == 2) ? a1 : (cg == 1) ? a2 : a3;
      float ig = 1.f / (1.f + __expf(-zi));
      float jt = 1.f - 2.f / (1.f + __expf(2.f * zj));
      float fg = 1.f / (1.f + __expf(-(zf + 1.0f)));      // FORGET_BIAS = 1
      float og = 1.f / (1.f + __expf(-zo));
      float c2 = fg * cstate + ig * jt;
      float h2 = og * (1.f - 2.f / (1.f + __expf(2.f * c2)));
      const bool act = wid ? do1 : do0;
      if (act) cstate = c2;
      float pub = (wid == 1 && p == 0) ? h1init : h2;
      float p0 = __shfl(pub, 0), p1 = __shfl(pub, 4);
      float p2 = __shfl(pub, 8), p3 = __shfl(pub, 12);
      if (lane == 0) {
        unsigned d0 = (unsigned)f2b(p0) | ((unsigned)f2b(p1) << 16);
        unsigned d1 = (unsigned)f2b(p2) | ((unsigned)f2b(p3) << 16);
        if (p < TSTEPS) {                       // publish data+tag in ONE 16B store
          u32x4 line = {d0, d1, 0u, (unsigned)(p + 1)};
          store_sc(xch + (wid ? 512 : 0) + (p & 1) * 256 + cu, line);
        }
        if (wid == 1 && p >= 1) {               // h1 trajectory (normal store)
          uint2 dd; dd.x = d0; dd.y = d1;
          *reinterpret_cast<uint2*>(h1all + (size_t)(p - 1) * 1024 + (cu << 2)) = dd;
        }
      }
    }

    if (useXb && (p + 1 < TSTEPS)) {
#pragma unroll
      for (int i = 0; i < 4; ++i) xcur[i] = xnxt[i];
    }
  }
}

// ---- logits[t, o] = h1all[t, :] @ Wd + bd ;  (512x1024)@(1024x512) ----
__global__ __launch_bounds__(256) void klogits(const unsigned short* __restrict__ h1all,
                                               const float* __restrict__ Wd,
                                               const float* __restrict__ bd,
                                               float* __restrict__ out) {
  __shared__ float hs[16][128];
  const int t  = threadIdx.x;
  const int o  = blockIdx.x * 64 + (t & 63);
  const int rq = t >> 6;
  const int r0 = blockIdx.y * 16;
  float acc[4] = {0.f, 0.f, 0.f, 0.f};
  for (int kc = 0; kc < 8; ++kc) {
    __syncthreads();
#pragma unroll
    for (int i = 0; i < 8; ++i) {
      int e = i * 256 + t;
      hs[e >> 7][e & 127] = b2f(h1all[(r0 + (e >> 7)) * 1024 + kc * 128 + (e & 127)]);
    }
    __syncthreads();
    for (int k = 0; k < 128; ++k) {
      float w = Wd[(size_t)(kc * 128 + k) * 512 + o];
#pragma unroll
      for (int r = 0; r < 4; ++r) acc[r] += hs[rq * 4 + r][k] * w;
    }
  }
  const float bv = bd[o];
#pragma unroll
  for (int r = 0; r < 4; ++r)
    out[(size_t)(r0 + rq * 4 + r) * 512 + o] = acc[r] + bv;
}

extern "C" void kernel_launch(void* const* d_in, const int* in_sizes, int n_in,
                              void* d_out, int out_size, void* d_ws, size_t ws_size,
                              hipStream_t stream) {
  (void)in_sizes; (void)n_in; (void)out_size;
  const float* X  = (const float*)d_in[0];
  const float* st = (const float*)d_in[1];
  const float* W0 = (const float*)d_in[2];
  const float* b0 = (const float*)d_in[3];
  const float* W1 = (const float*)d_in[4];
  const float* b1 = (const float*)d_in[5];
  const float* Wd = (const float*)d_in[6];
  const float* bd = (const float*)d_in[7];
  float* out = (float*)d_out;
  unsigned char* ws = (unsigned char*)d_ws;

  uint4*          pw    = (uint4*)(ws + WS_PW);
  u32x4*          xch   = (u32x4*)(ws + WS_XCH);
  unsigned short* h1all = (unsigned short*)(ws + WS_H1ALL);
  unsigned short* Xb63  = (unsigned short*)(ws + WS_XB);

  const float* X63     = X  + (size_t)63 * TSTEPS * 512;
  const float* state63 = st + (size_t)63 * 4096;

  const int useXb = (ws_size >= (size_t)WS_END) ? 1 : 0;   // ws_size fixed -> uniform

  kpack<<<7168, 256, 0, stream>>>(W0, W1, pw);
  if (useXb) kconvX63<<<256, 256, 0, stream>>>(X63, Xb63);
  kinith<<<1, 1024, 0, stream>>>(state63, xch);

  hipFuncSetAttribute((const void*)klstm, hipFuncAttributeMaxDynamicSharedMemorySize, 90112);
  klstm<<<256, 256, 90112, stream>>>(X63, Xb63, useXb, pw, xch, h1all,
                                     state63, b0, b1);

  klogits<<<dim3(8, 32), 256, 0, stream>>>(h1all, Wd, bd, out);
}

// Round 5
// 2009.120 us; speedup vs baseline: 4.1193x; 1.5805x over previous
//
#include <hip/hip_runtime.h>
#include <hip/hip_bf16.h>

// Problem: 2-layer LSTM. ys from lax.scan is (T, B, H); ys[:, -1, :] selects BATCH 63,
// all T=512 steps. Output logits[t, o] = h1[t] @ Wd + bd, (512, 512) fp32.
// Latency-bound serial chain: 513 pipelined phases (L0 step p || L1 step p-1).
// Exchange: tagged 16B data lines (sc0/sc1, LLC-coherent, no fences/atomics) +
// COMPACT per-block tag array so the per-phase poll is 1 load/lane on ONE wave.

#define TSTEPS 512

typedef short bf16x8 __attribute__((ext_vector_type(8)));
typedef float f32x4  __attribute__((ext_vector_type(4)));
typedef unsigned int u32x4 __attribute__((ext_vector_type(4)));

// ---- workspace layout (bytes) ----
#define WS_PW    0u          // packed weights: 256cu*4w*28slot*64lane*16B = 29360128
#define WS_XCH   29360128u   // data lines: 1024 x 16B (A:slot0,slot1 | B:slot0,slot1)
#define WS_TAG   29376512u   // compact tags: 256 u32 = 1024 B
#define WS_H1ALL 29377536u   // h1 trajectory [512][1024] bf16 = 1048576
#define WS_XB    30426112u   // batch-63 X in bf16: 512*512*2 = 524288
#define WS_END   30950400u

__device__ __forceinline__ unsigned short f2b(float x) {
  unsigned int u = __builtin_bit_cast(unsigned int, x);
  unsigned int r = (u + 0x7FFFu + ((u >> 16) & 1u)) >> 16;   // RNE
  return (unsigned short)r;
}
__device__ __forceinline__ float b2f(unsigned short u) {
  return __builtin_bit_cast(float, (unsigned int)u << 16);
}

// LLC-coherent (cache-bypassing) accesses: sc0 sc1 on gfx950.
__device__ __forceinline__ u32x4 load_sc(const u32x4* p) {
  u32x4 r;
  asm volatile("global_load_dwordx4 %0, %1, off sc0 sc1" : "=v"(r) : "v"(p));
  return r;
}
__device__ __forceinline__ void store_sc(u32x4* p, u32x4 v) {
  asm volatile("global_store_dwordx4 %0, %1, off sc0 sc1" :: "v"(p), "v"(v) : "memory");
}
__device__ __forceinline__ void store_sc_u32(unsigned* p, unsigned v) {
  asm volatile("global_store_dword %0, %1, off sc0 sc1" :: "v"(p), "v"(v) : "memory");
}

// ---- prep: pack W0/W1 (fp32) into per-(cu,wave,slot,lane) bf16 MFMA B-fragments ----
// k-permutation chosen so each consumer lane's h-columns are CONTIGUOUS:
//   x  slots i in [0,4):   W0 row k = w*128 + i*32 + q*8 + e
//   h0 slots i in [4,12):  W0 row k = 512 + w*256 + q*64 + (i-4)*8 + e
//   h0 slots i in [12,20): W1 row k = w*256 + q*64 + (i-12)*8 + e
//   h1 slots i in [20,28): W1 row k = 1024 + w*256 + q*64 + (i-20)*8 + e
// Column n = g*1024 + cu*4 + j with vc=lane&15, j=vc>>2, g=vc&3 (gate order i,j,f,o).
__global__ __launch_bounds__(256) void kpack(const float* __restrict__ W0,
                                             const float* __restrict__ W1,
                                             uint4* __restrict__ pw) {
  const int t    = blockIdx.x * 256 + threadIdx.x;   // 0..1835007
  const int lane = t & 63;
  const int rest = t >> 6;
  const int i    = rest % 28;
  const int cw   = rest / 28;          // cu*4 + w
  const int w    = cw & 3;
  const int cu   = cw >> 2;
  const int q  = lane >> 4, vc = lane & 15;
  const int n  = (vc & 3) * 1024 + (cu << 2) + (vc >> 2);
  const float* src; int k0;
  if (i < 4)       { src = W0; k0 = w * 128 + i * 32 + q * 8; }
  else if (i < 12) { src = W0; k0 = 512 + w * 256 + q * 64 + (i - 4) * 8; }
  else if (i < 20) { src = W1; k0 = w * 256 + q * 64 + (i - 12) * 8; }
  else             { src = W1; k0 = 1024 + w * 256 + q * 64 + (i - 20) * 8; }
  unsigned int wd[4];
#pragma unroll
  for (int e2 = 0; e2 < 4; ++e2) {
    unsigned int lo = f2b(src[(size_t)(k0 + 2 * e2    ) * 4096 + n]);
    unsigned int hi = f2b(src[(size_t)(k0 + 2 * e2 + 1) * 4096 + n]);
    wd[e2] = lo | (hi << 16);
  }
  uint4 v; v.x = wd[0]; v.y = wd[1]; v.z = wd[2]; v.w = wd[3];
  pw[t] = v;
}

// ---- prep: batch-63 X slice fp32 -> bf16 ----
__global__ __launch_bounds__(256) void kconvX63(const float* __restrict__ X63,
                                                unsigned short* __restrict__ Xb) {
  const int i = blockIdx.x * 256 + threadIdx.x;
  const float4 v = reinterpret_cast<const float4*>(X63)[i];
  ushort4 o;
  o.x = f2b(v.x); o.y = f2b(v.y); o.z = f2b(v.z); o.w = f2b(v.w);
  reinterpret_cast<ushort4*>(Xb)[i] = o;
}

// ---- prep: init exchange lines + tags. Lines [0,256)=A slot0, [256,512)=A slot1,
// [512,768)=B slot0, [768,1024)=B slot1. Tags and line-tags MUST be zeroed (0xAA poison).
__global__ __launch_bounds__(1024) void kinith(const float* __restrict__ state63,
                                               u32x4* __restrict__ xch,
                                               unsigned int* __restrict__ tags) {
  const int i  = threadIdx.x;            // 0..1023
  const int rg = i >> 8, cu = i & 255;
  u32x4 v = {0u, 0u, 0u, 0u};
  if (rg == 1) {                         // initial h0 (consumed at phase 0)
    v.x = (unsigned)f2b(state63[1024 + 4*cu])     | ((unsigned)f2b(state63[1024 + 4*cu + 1]) << 16);
    v.y = (unsigned)f2b(state63[1024 + 4*cu + 2]) | ((unsigned)f2b(state63[1024 + 4*cu + 3]) << 16);
  } else if (rg == 3) {                  // initial h1 (data unused until p=1 publish)
    v.x = (unsigned)f2b(state63[3072 + 4*cu])     | ((unsigned)f2b(state63[3072 + 4*cu + 1]) << 16);
    v.y = (unsigned)f2b(state63[3072 + 4*cu + 2]) | ((unsigned)f2b(state63[3072 + 4*cu + 3]) << 16);
  }
  xch[i] = v;
  if (i < 256) tags[i] = 0u;
}

// ---- persistent batch-63 2-layer LSTM ----
// 256 blocks (1/CU via 88KB dyn LDS) x 256 threads (4 waves). Weights in VGPRs.
// Phase p: L0 step p (p<512) and L1 step p-1 (p>=1).
// Sync: wave0 polls 256 compact tags (1 dwordx4/lane); data lines loaded ONCE and
// verified via embedded tags (bounded retry covers tag/data store ordering).
__global__ __launch_bounds__(256, 1) void klstm(
    const float* __restrict__ X63,               // fp32 fallback
    const unsigned short* __restrict__ Xb63,     // bf16 [512][512]
    const int useXb,
    const uint4* __restrict__ pw,
    u32x4* __restrict__ xch,
    unsigned int* __restrict__ tags,
    unsigned short* __restrict__ h1all,          // [512][1024] bf16
    const float* __restrict__ state63,
    const float* __restrict__ b0, const float* __restrict__ b1)
{
  extern __shared__ float lds[];                 // partials: 2 parity x 128 floats
  const int cu   = blockIdx.x;
  const int tid  = threadIdx.x;
  const int lane = tid & 63;
  const int wid  = tid >> 6;
  const int q = lane >> 4, vc = lane & 15;
  const int cg = vc & 3;
  const int hc = (cu << 2) | (vc >> 2);

  uint4 wreg[28];
#pragma unroll
  for (int i = 0; i < 28; ++i)
    wreg[i] = pw[(((cu << 2) | wid) * 28 + i) * 64 + lane];

  // wave0 mirrors layer0 cell across all 64 lanes; wave1 mirrors layer1.
  float cstate = 0.f, bias = 0.f, h1init = 0.f;
  if (wid == 0) { cstate = state63[hc];        bias = b0[cg * 1024 + hc]; }
  if (wid == 1) { cstate = state63[2048 + hc]; bias = b1[cg * 1024 + hc];
                  h1init = state63[3072 + hc]; }

  const int lbase = (wid << 6) | (q << 4);     // first data line of this lane's window
  const unsigned short* xb = Xb63 + (wid << 7) + (q << 3);
  const u32x4* tagp = reinterpret_cast<const u32x4*>(tags) + lane;  // tags[4l..4l+3]

  uint4 xcur[4], xnxt[4];
  if (useXb) {
#pragma unroll
    for (int i = 0; i < 4; ++i)
      xcur[i] = *reinterpret_cast<const uint4*>(xb + i * 32);
  }

  for (int p = 0; p <= TSTEPS; ++p) {
    const bool do0 = (p < TSTEPS);
    const bool do1 = (p >= 1);
    f32x4 acc0 = {0.f, 0.f, 0.f, 0.f};
    f32x4 acc1 = {0.f, 0.f, 0.f, 0.f};

    // x-part MFMAs first (independent of the exchange)
    if (do0) {
      bf16x8 ax[4];
      if (useXb) {
#pragma unroll
        for (int i = 0; i < 4; ++i) ax[i] = __builtin_bit_cast(bf16x8, xcur[i]);
      } else {
        const float* xs = X63 + p * 512 + (wid << 7) + (q << 3);
#pragma unroll
        for (int i = 0; i < 4; ++i) {
          float4 f0 = *reinterpret_cast<const float4*>(xs + i * 32);
          float4 f1 = *reinterpret_cast<const float4*>(xs + i * 32 + 4);
          bf16x8 a;
          a[0] = (short)f2b(f0.x); a[1] = (short)f2b(f0.y);
          a[2] = (short)f2b(f0.z); a[3] = (short)f2b(f0.w);
          a[4] = (short)f2b(f1.x); a[5] = (short)f2b(f1.y);
          a[6] = (short)f2b(f1.z); a[7] = (short)f2b(f1.w);
          ax[i] = a;
        }
      }
#pragma unroll
      for (int i = 0; i < 4; ++i)
        acc0 = __builtin_amdgcn_mfma_f32_16x16x32_bf16(
            ax[i], __builtin_bit_cast(bf16x8, wreg[i]), acc0, 0, 0, 0);
    }

    // ---- wave0 polls compact tags: all 256 blocks done with phase p-1? ----
    const unsigned tgt = (unsigned)p;
    if (wid == 0) {
      int guard = 0;
      while (true) {
        u32x4 tv = load_sc(tagp);
        asm volatile("s_waitcnt vmcnt(0)" ::: "memory");
        __builtin_amdgcn_sched_barrier(0);
        bool ok = (tv.x >= tgt) && (tv.y >= tgt) && (tv.z >= tgt) && (tv.w >= tgt);
        if (__all(ok) || ++guard > (1 << 15)) break;
      }
    }
    __syncthreads();                           // release waves 1..3

    // ---- data load ONCE + embedded-tag verify (bounded retry for ordering race) ----
    const int slotR = (p + 1) & 1;
    const u32x4* baA = xch + slotR * 256 + lbase;
    const u32x4* baB = xch + 512 + slotR * 256 + lbase;
    u32x4 la[16], lb[16];
    int guard2 = 0;
    while (true) {
#pragma unroll
      for (int j = 0; j < 16; ++j) la[j] = load_sc(baA + j);
#pragma unroll
      for (int j = 0; j < 16; ++j) lb[j] = load_sc(baB + j);
      asm volatile("s_waitcnt vmcnt(0)" ::: "memory");
      __builtin_amdgcn_sched_barrier(0);
      bool ok = true;
#pragma unroll
      for (int j = 0; j < 16; ++j)
        ok = ok && (la[j].w >= tgt) && (lb[j].w >= tgt);
      if (__all(ok) || ++guard2 > (1 << 12)) break;
    }

    // next-phase x prefetch (overlaps with MFMAs below)
    if (useXb && (p + 1 < TSTEPS)) {
#pragma unroll
      for (int i = 0; i < 4; ++i)
        xnxt[i] = *reinterpret_cast<const uint4*>(xb + (size_t)(p + 1) * 512 + i * 32);
    }

    // assemble contiguous-column fragments (lane window: 64 h-cols = 16 lines)
    bf16x8 ah0[8], ah1[8];
#pragma unroll
    for (int i = 0; i < 8; ++i) {
      u32x4 va = {la[2*i].x, la[2*i].y, la[2*i+1].x, la[2*i+1].y};
      u32x4 vb = {lb[2*i].x, lb[2*i].y, lb[2*i+1].x, lb[2*i+1].y};
      ah0[i] = __builtin_bit_cast(bf16x8, va);
      ah1[i] = __builtin_bit_cast(bf16x8, vb);
    }

    if (do0) {
#pragma unroll
      for (int i = 0; i < 8; ++i)
        acc0 = __builtin_amdgcn_mfma_f32_16x16x32_bf16(
            ah0[i], __builtin_bit_cast(bf16x8, wreg[4 + i]), acc0, 0, 0, 0);
    }
    if (do1) {
#pragma unroll
      for (int i = 0; i < 8; ++i) {
        acc1 = __builtin_amdgcn_mfma_f32_16x16x32_bf16(
            ah0[i], __builtin_bit_cast(bf16x8, wreg[12 + i]), acc1, 0, 0, 0);
        acc1 = __builtin_amdgcn_mfma_f32_16x16x32_bf16(
            ah1[i], __builtin_bit_cast(bf16x8, wreg[20 + i]), acc1, 0, 0, 0);
      }
    }

    // cross-wave partials (parity-doubled LDS)
    float* part = lds + ((p & 1) << 7);
    if (lane < 16) {
      part[(wid << 4) | lane]        = acc0[0];
      part[64 + ((wid << 4) | lane)] = acc1[0];
    }
    __syncthreads();                           // (A)

    // cell update + publish: wave0 = layer0, wave1 = layer1 (all 64 lanes mirror)
    if (wid < 2) {
      float z = bias;
#pragma unroll
      for (int w2 = 0; w2 < 4; ++w2) z += part[(wid << 6) + w2 * 16 + vc];
      float a1 = __shfl_xor(z, 1);
      float a2 = __shfl_xor(z, 2);
      float a3 = __shfl_xor(z, 3);
      float zi = (cg == 0) ? z : (cg == 1) ? a1 : (cg == 2) ? a2 : a3;
      float zj = (cg == 1) ? z : (cg == 0) ? a1 : (cg == 3) ? a2 : a3;
      float zf = (cg == 2) ? z : (cg == 3) ? a1 : (cg == 0) ? a2 : a3;
      float zo = (cg == 3) ? z : (cg == 2) ? a1 : (cg == 1) ? a2 : a3;
      float ig = 1.f / (1.f + __expf(-zi));
      float jt = 1.f - 2.f / (1.f + __expf(2.f * zj));
      float fg = 1.f / (1.f + __expf(-(zf + 1.0f)));      // FORGET_BIAS = 1
      float og = 1.f / (1.f + __expf(-zo));
      float c2 = fg * cstate + ig * jt;
      float h2 = og * (1.f - 2.f / (1.f + __expf(2.f * c2)));
      const bool act = wid ? do1 : do0;
      if (act) cstate = c2;
      float pub = (wid == 1 && p == 0) ? h1init : h2;
      float p0 = __shfl(pub, 0), p1 = __shfl(pub, 4);
      float p2 = __shfl(pub, 8), p3 = __shfl(pub, 12);
      if (lane == 0) {
        unsigned d0 = (unsigned)f2b(p0) | ((unsigned)f2b(p1) << 16);
        unsigned d1 = (unsigned)f2b(p2) | ((unsigned)f2b(p3) << 16);
        if (p < TSTEPS) {                       // data+embedded tag in ONE 16B store
          u32x4 line = {d0, d1, 0u, (unsigned)(p + 1)};
          store_sc(xch + (wid ? 512 : 0) + (p & 1) * 256 + cu, line);
        }
        if (wid == 1 && p >= 1) {               // h1 trajectory (normal store)
          uint2 dd; dd.x = d0; dd.y = d1;
          *reinterpret_cast<uint2*>(h1all + (size_t)(p - 1) * 1024 + (cu << 2)) = dd;
        }
      }
    }

    __syncthreads();                           // (B) drains publish stores (vmcnt)
    if (tid == 0 && p < TSTEPS)                // post compact tag for phase p
      store_sc_u32(tags + cu, (unsigned)(p + 1));

    if (useXb && (p + 1 < TSTEPS)) {
#pragma unroll
      for (int i = 0; i < 4; ++i) xcur[i] = xnxt[i];
    }
  }
}

// ---- logits[t, o] = h1all[t, :] @ Wd + bd ;  (512x1024)@(1024x512) ----
__global__ __launch_bounds__(256) void klogits(const unsigned short* __restrict__ h1all,
                                               const float* __restrict__ Wd,
                                               const float* __restrict__ bd,
                                               float* __restrict__ out) {
  __shared__ float hs[16][128];
  const int t  = threadIdx.x;
  const int o  = blockIdx.x * 64 + (t & 63);
  const int rq = t >> 6;
  const int r0 = blockIdx.y * 16;
  float acc[4] = {0.f, 0.f, 0.f, 0.f};
  for (int kc = 0; kc < 8; ++kc) {
    __syncthreads();
#pragma unroll
    for (int i = 0; i < 8; ++i) {
      int e = i * 256 + t;
      hs[e >> 7][e & 127] = b2f(h1all[(r0 + (e >> 7)) * 1024 + kc * 128 + (e & 127)]);
    }
    __syncthreads();
    for (int k = 0; k < 128; ++k) {
      float w = Wd[(size_t)(kc * 128 + k) * 512 + o];
#pragma unroll
      for (int r = 0; r < 4; ++r) acc[r] += hs[rq * 4 + r][k] * w;
    }
  }
  const float bv = bd[o];
#pragma unroll
  for (int r = 0; r < 4; ++r)
    out[(size_t)(r0 + rq * 4 + r) * 512 + o] = acc[r] + bv;
}

extern "C" void kernel_launch(void* const* d_in, const int* in_sizes, int n_in,
                              void* d_out, int out_size, void* d_ws, size_t ws_size,
                              hipStream_t stream) {
  (void)in_sizes; (void)n_in; (void)out_size;
  const float* X  = (const float*)d_in[0];
  const float* st = (const float*)d_in[1];
  const float* W0 = (const float*)d_in[2];
  const float* b0 = (const float*)d_in[3];
  const float* W1 = (const float*)d_in[4];
  const float* b1 = (const float*)d_in[5];
  const float* Wd = (const float*)d_in[6];
  const float* bd = (const float*)d_in[7];
  float* out = (float*)d_out;
  unsigned char* ws = (unsigned char*)d_ws;

  uint4*          pw    = (uint4*)(ws + WS_PW);
  u32x4*          xch   = (u32x4*)(ws + WS_XCH);
  unsigned int*   tags  = (unsigned int*)(ws + WS_TAG);
  unsigned short* h1all = (unsigned short*)(ws + WS_H1ALL);
  unsigned short* Xb63  = (unsigned short*)(ws + WS_XB);

  const float* X63     = X  + (size_t)63 * TSTEPS * 512;
  const float* state63 = st + (size_t)63 * 4096;

  const int useXb = (ws_size >= (size_t)WS_END) ? 1 : 0;   // ws_size fixed -> uniform

  kpack<<<7168, 256, 0, stream>>>(W0, W1, pw);
  if (useXb) kconvX63<<<256, 256, 0, stream>>>(X63, Xb63);
  kinith<<<1, 1024, 0, stream>>>(state63, xch, tags);

  hipFuncSetAttribute((const void*)klstm, hipFuncAttributeMaxDynamicSharedMemorySize, 90112);
  klstm<<<256, 256, 90112, stream>>>(X63, Xb63, useXb, pw, xch, tags, h1all,
                                     state63, b0, b1);

  klogits<<<dim3(8, 32), 256, 0, stream>>>(h1all, Wd, bd, out);
}

// Round 8
// 1199.025 us; speedup vs baseline: 6.9025x; 1.6756x over previous
//
#include <hip/hip_runtime.h>
#include <hip/hip_bf16.h>

// Problem: 2-layer LSTM. ys from lax.scan is (T, B, H); ys[:, -1, :] selects BATCH 63,
// all T=512 steps. Output logits[t, o] = h1[t] @ Wd + bd, (512, 512) fp32.
// Latency-bound serial chain: 513 pipelined phases (L0 step p || L1 step p-1).
// ONE LLC round trip per phase: producers publish {4 bf16 h-cols, pad, tag} per 16B
// sc0/sc1 line (single-copy atomic — validated by the R3-bench pass); wave0 polls the
// 256 A-lines, wave1 the 256 B-lines (4 lines = 64B per lane, per-line masked reload),
// then redistributes h0/h1 to all waves via LDS.
// R8 fix vs R6/R7: LDS redistribute needs 16 blocks x 144B = 2304 B PER ARRAY.
// R6/R7 placed h1 at 1280 and partials at 2560 -> h0 blocks 9..15 overwrote h1
// blocks 0..7, h1 blocks 9..15 overwrote partials => ~0.12 absmax. Now h0@0, h1@2304,
// partials@4608.

#define TSTEPS 512

typedef short bf16x8 __attribute__((ext_vector_type(8)));
typedef float f32x4  __attribute__((ext_vector_type(4)));
typedef unsigned int u32x4 __attribute__((ext_vector_type(4)));

// ---- workspace layout (bytes) ----
#define WS_PW    0u          // packed weights: 256cu*4w*28slot*64lane*16B = 29360128
#define WS_XCH   29360128u   // data lines: 1024 x 16B (A:slot0,slot1 | B:slot0,slot1)
#define WS_H1ALL 29377536u   // h1 trajectory [512][1024] bf16 = 1048576
#define WS_XB    30426112u   // batch-63 X in bf16: 512*512*2 = 524288
#define WS_END   30950400u

__device__ __forceinline__ unsigned short f2b(float x) {
  unsigned int u = __builtin_bit_cast(unsigned int, x);
  unsigned int r = (u + 0x7FFFu + ((u >> 16) & 1u)) >> 16;   // RNE
  return (unsigned short)r;
}
__device__ __forceinline__ float b2f(unsigned short u) {
  return __builtin_bit_cast(float, (unsigned int)u << 16);
}

// LLC-coherent (cache-bypassing) accesses: sc0 sc1 on gfx950.
__device__ __forceinline__ u32x4 load_sc(const u32x4* p) {
  u32x4 r;
  asm volatile("global_load_dwordx4 %0, %1, off sc0 sc1" : "=v"(r) : "v"(p));
  return r;
}
__device__ __forceinline__ void store_sc(u32x4* p, u32x4 v) {
  asm volatile("global_store_dwordx4 %0, %1, off sc0 sc1" :: "v"(p), "v"(v) : "memory");
}

// ---- prep: pack W0/W1 (fp32) into per-(cu,wave,slot,lane) bf16 MFMA B-fragments ----
//   x  slots i in [0,4):   W0 row k = w*128 + i*32 + q*8 + e
//   h0 slots i in [4,12):  W0 row k = 512 + w*256 + q*64 + (i-4)*8 + e
//   h0 slots i in [12,20): W1 row k = w*256 + q*64 + (i-12)*8 + e
//   h1 slots i in [20,28): W1 row k = 1024 + w*256 + q*64 + (i-20)*8 + e
// Column n = g*1024 + cu*4 + j with vc=lane&15, j=vc>>2, g=vc&3 (gate order i,j,f,o).
__global__ __launch_bounds__(256) void kpack(const float* __restrict__ W0,
                                             const float* __restrict__ W1,
                                             uint4* __restrict__ pw) {
  const int t    = blockIdx.x * 256 + threadIdx.x;   // 0..1835007
  const int lane = t & 63;
  const int rest = t >> 6;
  const int i    = rest % 28;
  const int cw   = rest / 28;          // cu*4 + w
  const int w    = cw & 3;
  const int cu   = cw >> 2;
  const int q  = lane >> 4, vc = lane & 15;
  const int n  = (vc & 3) * 1024 + (cu << 2) + (vc >> 2);
  const float* src; int k0;
  if (i < 4)       { src = W0; k0 = w * 128 + i * 32 + q * 8; }
  else if (i < 12) { src = W0; k0 = 512 + w * 256 + q * 64 + (i - 4) * 8; }
  else if (i < 20) { src = W1; k0 = w * 256 + q * 64 + (i - 12) * 8; }
  else             { src = W1; k0 = 1024 + w * 256 + q * 64 + (i - 20) * 8; }
  unsigned int wd[4];
#pragma unroll
  for (int e2 = 0; e2 < 4; ++e2) {
    unsigned int lo = f2b(src[(size_t)(k0 + 2 * e2    ) * 4096 + n]);
    unsigned int hi = f2b(src[(size_t)(k0 + 2 * e2 + 1) * 4096 + n]);
    wd[e2] = lo | (hi << 16);
  }
  uint4 v; v.x = wd[0]; v.y = wd[1]; v.z = wd[2]; v.w = wd[3];
  pw[t] = v;
}

// ---- prep: batch-63 X slice fp32 -> bf16 ----
__global__ __launch_bounds__(256) void kconvX63(const float* __restrict__ X63,
                                                unsigned short* __restrict__ Xb) {
  const int i = blockIdx.x * 256 + threadIdx.x;
  const float4 v = reinterpret_cast<const float4*>(X63)[i];
  ushort4 o;
  o.x = f2b(v.x); o.y = f2b(v.y); o.z = f2b(v.z); o.w = f2b(v.w);
  reinterpret_cast<ushort4*>(Xb)[i] = o;
}

// ---- prep: init exchange lines. [0,256)=A slot0, [256,512)=A slot1,
// [512,768)=B slot0, [768,1024)=B slot1. All line tags (.w) MUST be 0 (0xAA poison).
__global__ __launch_bounds__(1024) void kinith(const float* __restrict__ state63,
                                               u32x4* __restrict__ xch) {
  const int i  = threadIdx.x;            // 0..1023
  const int rg = i >> 8, cu = i & 255;
  u32x4 v = {0u, 0u, 0u, 0u};
  if (rg == 1) {                         // initial h0 (consumed at phase 0, tgt=0 trivial)
    v.x = (unsigned)f2b(state63[1024 + 4*cu])     | ((unsigned)f2b(state63[1024 + 4*cu + 1]) << 16);
    v.y = (unsigned)f2b(state63[1024 + 4*cu + 2]) | ((unsigned)f2b(state63[1024 + 4*cu + 3]) << 16);
  } else if (rg == 3) {                  // initial h1 (republished at p=0 with tag 1)
    v.x = (unsigned)f2b(state63[3072 + 4*cu])     | ((unsigned)f2b(state63[3072 + 4*cu + 1]) << 16);
    v.y = (unsigned)f2b(state63[3072 + 4*cu + 2]) | ((unsigned)f2b(state63[3072 + 4*cu + 3]) << 16);
  }
  xch[i] = v;
}

// ---- persistent batch-63 2-layer LSTM ----
// 256 blocks (1/CU via 88KB dyn LDS) x 256 threads (4 waves). Weights in VGPRs.
// Phase p: wave0 polls+loads the 256 A-lines (h0[p-1]), wave1 the 256 B-lines
// (h1[p-2]); 4 lines (64B) per lane, per-line masked reload; LDS redistribute
// ([16 blk][144B] per array); all waves read fragments, MFMA, partial-reduce;
// waves 0/1 run the cells and publish data+tag in one 16B store.
__global__ __launch_bounds__(256, 1) void klstm(
    const float* __restrict__ X63,               // fp32 fallback
    const unsigned short* __restrict__ Xb63,     // bf16 [512][512]
    const int useXb,
    const uint4* __restrict__ pw,
    u32x4* __restrict__ xch,
    unsigned short* __restrict__ h1all,          // [512][1024] bf16
    const float* __restrict__ state63,
    const float* __restrict__ b0, const float* __restrict__ b1)
{
  extern __shared__ char ldsraw[];
  // LDS map (R8-fixed): h0 [16 blk][144B] @0 (2304B); h1 @2304 (2304B);
  // partials @4608 (2 parity x 128 f32 = 1024B). Total 5632B used.
  const int cu   = blockIdx.x;
  const int tid  = threadIdx.x;
  const int lane = tid & 63;
  const int wid  = tid >> 6;
  const int q = lane >> 4, vc = lane & 15;
  const int cg = vc & 3;
  const int hc = (cu << 2) | (vc >> 2);

  uint4 wreg[28];
#pragma unroll
  for (int i = 0; i < 28; ++i)
    wreg[i] = pw[(((cu << 2) | wid) * 28 + i) * 64 + lane];

  // wave0 = layer0 cell (64-lane mirror), wave1 = layer1 cell.
  float cstate = 0.f, bias = 0.f, h1init = 0.f;
  if (wid == 0) { cstate = state63[hc];        bias = b0[cg * 1024 + hc]; }
  if (wid == 1) { cstate = state63[2048 + hc]; bias = b1[cg * 1024 + hc];
                  h1init = state63[3072 + hc]; }

  const unsigned short* xb = Xb63 + (wid << 7) + (q << 3);
  const char* fragp0 = ldsraw +        (((wid << 2) | q) * 144);
  const char* fragp1 = ldsraw + 2304 + (((wid << 2) | q) * 144);

  uint4 xcur[4], xnxt[4];
  if (useXb) {
#pragma unroll
    for (int i = 0; i < 4; ++i)
      xcur[i] = *reinterpret_cast<const uint4*>(xb + i * 32);
  }

  for (int p = 0; p <= TSTEPS; ++p) {
    const bool do0 = (p < TSTEPS);
    const bool do1 = (p >= 1);
    const unsigned tgt = (unsigned)p;
    f32x4 acc0 = {0.f, 0.f, 0.f, 0.f};
    f32x4 acc1 = {0.f, 0.f, 0.f, 0.f};

    // issue poll round 0 ASAP (waves 0/1); x-MFMAs overlap the flight time
    const u32x4* pbase = xch + (wid ? 512 : 0) + (((p + 1) & 1) << 8) + (lane << 2);
    u32x4 ln0, ln1, ln2, ln3;
    if (wid < 2) {
      ln0 = load_sc(pbase + 0); ln1 = load_sc(pbase + 1);
      ln2 = load_sc(pbase + 2); ln3 = load_sc(pbase + 3);
    }

    // next-phase x prefetch (normal cached loads; independent)
    if (useXb && (p + 1 < TSTEPS)) {
#pragma unroll
      for (int i = 0; i < 4; ++i)
        xnxt[i] = *reinterpret_cast<const uint4*>(xb + (size_t)(p + 1) * 512 + i * 32);
    }

    // x-part MFMAs (independent of the exchange)
    if (do0) {
      bf16x8 ax[4];
      if (useXb) {
#pragma unroll
        for (int i = 0; i < 4; ++i) ax[i] = __builtin_bit_cast(bf16x8, xcur[i]);
      } else {
        const float* xs = X63 + p * 512 + (wid << 7) + (q << 3);
#pragma unroll
        for (int i = 0; i < 4; ++i) {
          float4 f0 = *reinterpret_cast<const float4*>(xs + i * 32);
          float4 f1 = *reinterpret_cast<const float4*>(xs + i * 32 + 4);
          bf16x8 a;
          a[0] = (short)f2b(f0.x); a[1] = (short)f2b(f0.y);
          a[2] = (short)f2b(f0.z); a[3] = (short)f2b(f0.w);
          a[4] = (short)f2b(f1.x); a[5] = (short)f2b(f1.y);
          a[6] = (short)f2b(f1.z); a[7] = (short)f2b(f1.w);
          ax[i] = a;
        }
      }
#pragma unroll
      for (int i = 0; i < 4; ++i)
        acc0 = __builtin_amdgcn_mfma_f32_16x16x32_bf16(
            ax[i], __builtin_bit_cast(bf16x8, wreg[i]), acc0, 0, 0, 0);
    }

    // ---- poll + load in one: per-line masked reload until all 4 tags >= p ----
    if (wid < 2) {
      int guard = 0;
      while (true) {
        asm volatile("s_waitcnt vmcnt(0)" ::: "memory");
        __builtin_amdgcn_sched_barrier(0);
        const unsigned m = (ln0.w < tgt ? 1u : 0u) | (ln1.w < tgt ? 2u : 0u) |
                           (ln2.w < tgt ? 4u : 0u) | (ln3.w < tgt ? 8u : 0u);
        if (!__any(m != 0u) || ++guard > (1 << 15)) break;
        if (m & 1u) ln0 = load_sc(pbase + 0);
        if (m & 2u) ln1 = load_sc(pbase + 1);
        if (m & 4u) ln2 = load_sc(pbase + 2);
        if (m & 8u) ln3 = load_sc(pbase + 3);
      }
      // redistribute: lane l holds h-cols 16l..16l+15 (8B data per line) ->
      // LDS block (l>>2) covers cols [64*(l>>2), +64), offset (l&3)*32 + {0,16}
      char* dst = ldsraw + (wid ? 2304 : 0) + ((lane >> 2) * 144) + ((lane & 3) * 32);
      u32x4 w0 = {ln0.x, ln0.y, ln1.x, ln1.y};
      u32x4 w1 = {ln2.x, ln2.y, ln3.x, ln3.y};
      *reinterpret_cast<u32x4*>(dst)      = w0;
      *reinterpret_cast<u32x4*>(dst + 16) = w1;
    }
    __syncthreads();                           // (S1) h0/h1 ready in LDS

    // fragment reads: slot i covers k = wid*256 + q*64 + i*8 (+e); 16-lane broadcast
    bf16x8 ah0[8], ah1[8];
#pragma unroll
    for (int i = 0; i < 8; ++i) {
      ah0[i] = *reinterpret_cast<const bf16x8*>(fragp0 + i * 16);
      ah1[i] = *reinterpret_cast<const bf16x8*>(fragp1 + i * 16);
    }

    if (do0) {
#pragma unroll
      for (int i = 0; i < 8; ++i)
        acc0 = __builtin_amdgcn_mfma_f32_16x16x32_bf16(
            ah0[i], __builtin_bit_cast(bf16x8, wreg[4 + i]), acc0, 0, 0, 0);
    }
    if (do1) {
#pragma unroll
      for (int i = 0; i < 8; ++i) {
        acc1 = __builtin_amdgcn_mfma_f32_16x16x32_bf16(
            ah0[i], __builtin_bit_cast(bf16x8, wreg[12 + i]), acc1, 0, 0, 0);
        acc1 = __builtin_amdgcn_mfma_f32_16x16x32_bf16(
            ah1[i], __builtin_bit_cast(bf16x8, wreg[20 + i]), acc1, 0, 0, 0);
      }
    }

    // cross-wave partials (parity-doubled)
    float* part = reinterpret_cast<float*>(ldsraw + 4608) + ((p & 1) << 7);
    if (lane < 16) {
      part[(wid << 4) | lane]        = acc0[0];
      part[64 + ((wid << 4) | lane)] = acc1[0];
    }
    __syncthreads();                           // (S2)

    // cell update + publish (wave0 = L0, wave1 = L1; 64-lane mirror)
    if (wid < 2) {
      float z = bias;
#pragma unroll
      for (int w2 = 0; w2 < 4; ++w2) z += part[(wid << 6) + w2 * 16 + vc];
      float a1 = __shfl_xor(z, 1);
      float a2 = __shfl_xor(z, 2);
      float a3 = __shfl_xor(z, 3);
      float zi = (cg == 0) ? z : (cg == 1) ? a1 : (cg == 2) ? a2 : a3;
      float zj = (cg == 1) ? z : (cg == 0) ? a1 : (cg == 3) ? a2 : a3;
      float zf = (cg == 2) ? z : (cg == 3) ? a1 : (cg == 0) ? a2 : a3;
      float zo = (cg == 3) ? z : (cg == 2) ? a1 : (cg == 1) ? a2 : a3;
      float ig = 1.f / (1.f + __expf(-zi));
      float jt = 1.f - 2.f / (1.f + __expf(2.f * zj));
      float fg = 1.f / (1.f + __expf(-(zf + 1.0f)));      // FORGET_BIAS = 1
      float og = 1.f / (1.f + __expf(-zo));
      float c2 = fg * cstate + ig * jt;
      float h2 = og * (1.f - 2.f / (1.f + __expf(2.f * c2)));
      const bool act = wid ? do1 : do0;
      if (act) cstate = c2;
      float pub = (wid == 1 && p == 0) ? h1init : h2;
      float p0 = __shfl(pub, 0), p1 = __shfl(pub, 4);
      float p2 = __shfl(pub, 8), p3 = __shfl(pub, 12);
      if (lane == 0) {
        unsigned d0 = (unsigned)f2b(p0) | ((unsigned)f2b(p1) << 16);
        unsigned d1 = (unsigned)f2b(p2) | ((unsigned)f2b(p3) << 16);
        if (p < TSTEPS) {                      // data + tag p+1 in ONE 16B store
          u32x4 line = {d0, d1, 0u, (unsigned)(p + 1)};
          store_sc(xch + (wid ? 512 : 0) + ((p & 1) << 8) + cu, line);
        }
        if (wid == 1 && p >= 1) {              // h1 trajectory (normal store)
          uint2 dd; dd.x = d0; dd.y = d1;
          *reinterpret_cast<uint2*>(h1all + (size_t)(p - 1) * 1024 + (cu << 2)) = dd;
        }
      }
    }

    if (useXb && (p + 1 < TSTEPS)) {
#pragma unroll
      for (int i = 0; i < 4; ++i) xcur[i] = xnxt[i];
    }
  }
}

// ---- logits[t, o] = h1all[t, :] @ Wd + bd ;  (512x1024)@(1024x512) ----
__global__ __launch_bounds__(256) void klogits(const unsigned short* __restrict__ h1all,
                                               const float* __restrict__ Wd,
                                               const float* __restrict__ bd,
                                               float* __restrict__ out) {
  __shared__ float hs[16][128];
  const int t  = threadIdx.x;
  const int o  = blockIdx.x * 64 + (t & 63);
  const int rq = t >> 6;
  const int r0 = blockIdx.y * 16;
  float acc[4] = {0.f, 0.f, 0.f, 0.f};
  for (int kc = 0; kc < 8; ++kc) {
    __syncthreads();
#pragma unroll
    for (int i = 0; i < 8; ++i) {
      int e = i * 256 + t;
      hs[e >> 7][e & 127] = b2f(h1all[(r0 + (e >> 7)) * 1024 + kc * 128 + (e & 127)]);
    }
    __syncthreads();
    for (int k = 0; k < 128; ++k) {
      float w = Wd[(size_t)(kc * 128 + k) * 512 + o];
#pragma unroll
      for (int r = 0; r < 4; ++r) acc[r] += hs[rq * 4 + r][k] * w;
    }
  }
  const float bv = bd[o];
#pragma unroll
  for (int r = 0; r < 4; ++r)
    out[(size_t)(r0 + rq * 4 + r) * 512 + o] = acc[r] + bv;
}

extern "C" void kernel_launch(void* const* d_in, const int* in_sizes, int n_in,
                              void* d_out, int out_size, void* d_ws, size_t ws_size,
                              hipStream_t stream) {
  (void)in_sizes; (void)n_in; (void)out_size;
  const float* X  = (const float*)d_in[0];
  const float* st = (const float*)d_in[1];
  const float* W0 = (const float*)d_in[2];
  const float* b0 = (const float*)d_in[3];
  const float* W1 = (const float*)d_in[4];
  const float* b1 = (const float*)d_in[5];
  const float* Wd = (const float*)d_in[6];
  const float* bd = (const float*)d_in[7];
  float* out = (float*)d_out;
  unsigned char* ws = (unsigned char*)d_ws;

  uint4*          pw    = (uint4*)(ws + WS_PW);
  u32x4*          xch   = (u32x4*)(ws + WS_XCH);
  unsigned short* h1all = (unsigned short*)(ws + WS_H1ALL);
  unsigned short* Xb63  = (unsigned short*)(ws + WS_XB);

  const float* X63     = X  + (size_t)63 * TSTEPS * 512;
  const float* state63 = st + (size_t)63 * 4096;

  const int useXb = (ws_size >= (size_t)WS_END) ? 1 : 0;   // ws_size fixed -> uniform

  kpack<<<7168, 256, 0, stream>>>(W0, W1, pw);
  if (useXb) kconvX63<<<256, 256, 0, stream>>>(X63, Xb63);
  kinith<<<1, 1024, 0, stream>>>(state63, xch);

  hipFuncSetAttribute((const void*)klstm, hipFuncAttributeMaxDynamicSharedMemorySize, 90112);
  klstm<<<256, 256, 90112, stream>>>(X63, Xb63, useXb, pw, xch, h1all,
                                     state63, b0, b1);

  klogits<<<dim3(8, 32), 256, 0, stream>>>(h1all, Wd, bd, out);
}